// Round 1
// baseline (317.394 us; speedup 1.0000x reference)
//
#include <hip/hip_runtime.h>
#include <stdint.h>

// ---------------------------------------------------------------------------
// SelfAttn: B=4, W=H=64, C=256, C2=128, N=W*H=4096.
// pq = raw q buffer viewed [128,4096]  (Q_rows[n,c] = q_flat[c*4096+n])
// pv = raw v buffer viewed [256,4096]  (natural layout == PV B-operand layout)
// energy = Qrm @ Krm^T (K=128), softmax over keys, O[n,c] = sum_m P[n,m] V[m,c]
// final[b, c*4096+n] = gamma*O[n,c]/l[n] + x[b, c*4096+n]
// ---------------------------------------------------------------------------

typedef __attribute__((ext_vector_type(8))) short  short8;   // 8 x bf16 (4 VGPRs)
typedef __attribute__((ext_vector_type(4))) float  f32x4;
typedef __attribute__((ext_vector_type(4))) float  f32x4v;
typedef __attribute__((ext_vector_type(4))) unsigned short u16x4;

#define MFMA_BF16 __builtin_amdgcn_mfma_f32_16x16x32_bf16

__device__ __forceinline__ unsigned short f2bf(float f) {
    union { float f; uint32_t u; } v; v.f = f;
    uint32_t r = (v.u + 0x7FFFu + ((v.u >> 16) & 1u)) >> 16;   // RNE
    return (unsigned short)r;
}
__device__ __forceinline__ float bf2f(unsigned short h) {
    union { uint32_t u; float f; } v; v.u = ((uint32_t)h) << 16;
    return v.f;
}

// --- K1a: Wt[512][256] bf16 (transposed, fused qkv) + bias[512] f32 --------
__global__ void prep_w(const float* __restrict__ Wq, const float* __restrict__ bq,
                       const float* __restrict__ Wk, const float* __restrict__ bk,
                       const float* __restrict__ Wv, const float* __restrict__ bv,
                       unsigned short* __restrict__ Wt, float* __restrict__ bias) {
    int g = blockIdx.x * 256 + threadIdx.x;           // 512*256 = 131072 threads
    int c = g & 255, d = g >> 8;
    float val;
    if (d < 128)      val = Wq[c * 128 + d];
    else if (d < 256) val = Wk[c * 128 + (d - 128)];
    else              val = Wv[c * 256 + (d - 256)];
    Wt[d * 256 + c] = f2bf(val);
    if (g < 512) {
        float bb;
        if (g < 128)      bb = bq[g];
        else if (g < 256) bb = bk[g - 128];
        else              bb = bv[g - 256];
        bias[g] = bb;
    }
}

// --- K1b: x (fp32) -> xbf (bf16), 4 elems/thread ---------------------------
__global__ void conv_x(const float* __restrict__ x, unsigned short* __restrict__ xbf) {
    int g = blockIdx.x * 256 + threadIdx.x;
    int idx = g * 4;
    f32x4v v = *(const f32x4v*)(x + idx);
    u16x4 o;
    o[0] = f2bf(v[0]); o[1] = f2bf(v[1]); o[2] = f2bf(v[2]); o[3] = f2bf(v[3]);
    *(u16x4*)(xbf + idx) = o;
}

// --- K2: fused QKV projection GEMM [16384,256]x[256,512], MFMA bf16 --------
// Epilogue routes: d<128 -> Qrm[n,c] scatter; d<256 -> Krm; d>=256 -> Vbf natural.
__global__ __launch_bounds__(256) void proj(
        const unsigned short* __restrict__ xbf, const unsigned short* __restrict__ Wt,
        const float* __restrict__ bias,
        unsigned short* __restrict__ Qrm, unsigned short* __restrict__ Krm,
        unsigned short* __restrict__ Vbf) {
    int tid = threadIdx.x;
    int wave = tid >> 6, lane = tid & 63;
    int l16 = lane & 15, quad = lane >> 4;
    int p0w = blockIdx.x * 64 + wave * 16;            // 16 pixel-rows per wave

    short8 af[8];                                      // A-frags: x row, K=256
    const short8* xrow = (const short8*)(xbf + (p0w + l16) * 256);
    #pragma unroll
    for (int kk = 0; kk < 8; ++kk) af[kk] = xrow[kk * 4 + quad];

    for (int dt2 = 0; dt2 < 16; ++dt2) {
        int d0 = dt2 * 32;
        f32x4 accA = {0.f,0.f,0.f,0.f}, accB = {0.f,0.f,0.f,0.f};
        #pragma unroll
        for (int kk = 0; kk < 8; ++kk) {
            short8 bA = *(const short8*)(Wt + (d0 + l16) * 256 + kk * 32 + quad * 8);
            short8 bB = *(const short8*)(Wt + (d0 + 16 + l16) * 256 + kk * 32 + quad * 8);
            accA = MFMA_BF16(af[kk], bA, accA, 0, 0, 0);
            accB = MFMA_BF16(af[kk], bB, accB, 0, 0, 0);
        }
        #pragma unroll
        for (int half = 0; half < 2; ++half) {
            f32x4 acc = half ? accB : accA;
            int d = d0 + half * 16 + l16;              // C/D: col = lane&15
            float bval = bias[d];
            #pragma unroll
            for (int reg = 0; reg < 4; ++reg) {
                int p = p0w + quad * 4 + reg;          // C/D: row = quad*4+reg
                int b = p >> 12, pp = p & 4095;
                unsigned short hv = f2bf(acc[reg] + bval);
                if (d0 < 128) {
                    int n = ((pp & 31) << 7) | d;      // flat = pp*128+d -> (c,n)
                    int cc = pp >> 5;
                    Qrm[(b << 19) + n * 128 + cc] = hv;
                } else if (d0 < 256) {
                    int dk = d - 128;
                    int n = ((pp & 31) << 7) | dk;
                    int cc = pp >> 5;
                    Krm[(b << 19) + n * 128 + cc] = hv;
                } else {
                    int dv = d - 256;
                    Vbf[(b << 20) + pp * 256 + dv] = hv;  // natural == pv layout
                }
            }
        }
    }
}

// --- K3: flash attention, 4-way key split ----------------------------------
// grid 512 = 4 batch * 32 qtiles * 4 ksplits; 4 waves * 32 queries each.
__global__ __launch_bounds__(256, 2) void attn(
        const unsigned short* __restrict__ Qrm, const unsigned short* __restrict__ Krm,
        const unsigned short* __restrict__ Vbf, unsigned short* __restrict__ Opart,
        float* __restrict__ Mpart, float* __restrict__ Lpart) {

    // Ks[64][136] (8704 u16) overlaid with Ps[4][32*72] (9216 u16): phases
    // separated by a barrier. Vs[256][72]. Total LDS 55296 B -> 2 WG/CU.
    __shared__ unsigned short KP[9216];
    __shared__ unsigned short Vs[256 * 72];

    int bid = blockIdx.x;
    int ks = bid & 3, qt = (bid >> 2) & 31, b = bid >> 7;
    int tid = threadIdx.x;
    int wave = tid >> 6, lane = tid & 63;
    int l16 = lane & 15, quad = lane >> 4;

    const unsigned short* Qb = Qrm + (b << 19);
    const unsigned short* Kb = Krm + (b << 19);
    const unsigned short* Vb = Vbf + (b << 20);
    unsigned short* Ps = KP + wave * (32 * 72);

    int n0 = qt * 128 + wave * 32;

    // Q A-frags: resident for whole kernel (A: m=lane&15, k=quad*8+j)
    short8 qf[2][4];
    #pragma unroll
    for (int r = 0; r < 2; ++r)
        #pragma unroll
        for (int kk = 0; kk < 4; ++kk)
            qf[r][kk] = *(const short8*)(Qb + (n0 + r * 16 + l16) * 128 + kk * 32 + quad * 8);

    f32x4 O[2][16];
    #pragma unroll
    for (int r = 0; r < 2; ++r)
        #pragma unroll
        for (int t = 0; t < 16; ++t) O[r][t] = (f32x4){0.f,0.f,0.f,0.f};
    float m_run[2][4], l_run[2][4];
    #pragma unroll
    for (int r = 0; r < 2; ++r)
        #pragma unroll
        for (int reg = 0; reg < 4; ++reg) { m_run[r][reg] = -1e30f; l_run[r][reg] = 0.f; }

    const int m_base = ks * 1024;
    #pragma unroll 1
    for (int kt = 0; kt < 16; ++kt) {
        int m0 = m_base + kt * 64;
        __syncthreads();                               // protect prev tile KP/Vs
        #pragma unroll
        for (int i = 0; i < 4; ++i) {                  // stage K-tile [64][128]
            int idx = i * 256 + tid, row = idx >> 4, ch = idx & 15;
            *(short8*)(KP + row * 136 + ch * 8) =
                *(const short8*)(Kb + (m0 + row) * 128 + ch * 8);
        }
        #pragma unroll
        for (int i = 0; i < 8; ++i) {                  // stage V-tile [256][64]
            int idx = i * 256 + tid, row = idx >> 3, ch = idx & 7;
            *(short8*)(Vs + row * 72 + ch * 8) =
                *(const short8*)(Vb + row * 4096 + m0 + ch * 8);
        }
        __syncthreads();

        f32x4 S[2][4];
        #pragma unroll
        for (int r = 0; r < 2; ++r)
            #pragma unroll
            for (int j = 0; j < 4; ++j) S[r][j] = (f32x4){0.f,0.f,0.f,0.f};
        #pragma unroll
        for (int ksub = 0; ksub < 4; ++ksub) {
            #pragma unroll
            for (int kk = 0; kk < 4; ++kk) {
                short8 bk = *(const short8*)(KP + (ksub * 16 + l16) * 136 + kk * 32 + quad * 8);
                S[0][ksub] = MFMA_BF16(qf[0][kk], bk, S[0][ksub], 0, 0, 0);
                S[1][ksub] = MFMA_BF16(qf[1][kk], bk, S[1][ksub], 0, 0, 0);
            }
        }
        __syncthreads();                               // all waves done with Ks -> Ps overlay ok

        // online softmax: row = quad*4+reg, col = lane&15 (+16*ksub)
        #pragma unroll
        for (int r = 0; r < 2; ++r) {
            #pragma unroll
            for (int reg = 0; reg < 4; ++reg) {
                float mx = fmaxf(fmaxf(S[r][0][reg], S[r][1][reg]),
                                 fmaxf(S[r][2][reg], S[r][3][reg]));
                #pragma unroll
                for (int d = 1; d < 16; d <<= 1) mx = fmaxf(mx, __shfl_xor(mx, d));
                float mnew  = fmaxf(m_run[r][reg], mx);
                float alpha = __expf(m_run[r][reg] - mnew);
                float rs = 0.f;
                #pragma unroll
                for (int ksub = 0; ksub < 4; ++ksub) {
                    float pv = __expf(S[r][ksub][reg] - mnew);
                    S[r][ksub][reg] = pv;
                    rs += pv;
                }
                #pragma unroll
                for (int d = 1; d < 16; d <<= 1) rs += __shfl_xor(rs, d);
                l_run[r][reg] = l_run[r][reg] * alpha + rs;
                m_run[r][reg] = mnew;
                #pragma unroll
                for (int t = 0; t < 16; ++t) O[r][t][reg] *= alpha;
                #pragma unroll
                for (int ksub = 0; ksub < 4; ++ksub)
                    Ps[(r * 16 + quad * 4 + reg) * 72 + ksub * 16 + l16] = f2bf(S[r][ksub][reg]);
            }
        }

        // PV: O[n,c] += P[n,m] V[m,c]
        #pragma unroll
        for (int s = 0; s < 2; ++s) {
            short8 a0 = *(const short8*)(Ps + (l16) * 72 + s * 32 + quad * 8);
            short8 a1 = *(const short8*)(Ps + (16 + l16) * 72 + s * 32 + quad * 8);
            #pragma unroll
            for (int t = 0; t < 16; ++t) {
                short8 bv = *(const short8*)(Vs + (t * 16 + l16) * 72 + s * 32 + quad * 8);
                O[0][t] = MFMA_BF16(a0, bv, O[0][t], 0, 0, 0);
                O[1][t] = MFMA_BF16(a1, bv, O[1][t], 0, 0, 0);
            }
        }
    }

    // epilogue: unnormalized O (bf16) + per-row m,l
    unsigned short* Op = Opart + ((size_t)(ks * 4 + b) << 20);
    #pragma unroll
    for (int r = 0; r < 2; ++r)
        #pragma unroll
        for (int t = 0; t < 16; ++t)
            #pragma unroll
            for (int reg = 0; reg < 4; ++reg) {
                int n = n0 + r * 16 + quad * 4 + reg;
                int c = t * 16 + l16;
                Op[n * 256 + c] = f2bf(O[r][t][reg]);
            }
    if (l16 == 0) {
        #pragma unroll
        for (int r = 0; r < 2; ++r)
            #pragma unroll
            for (int reg = 0; reg < 4; ++reg) {
                int n = n0 + r * 16 + quad * 4 + reg;
                Mpart[(ks * 4 + b) * 4096 + n] = m_run[r][reg];
                Lpart[(ks * 4 + b) * 4096 + n] = l_run[r][reg];
            }
    }
}

// --- K4: merge 4 key-splits, normalize, gamma*O+x, transpose [n,c]->[c,n] --
__global__ __launch_bounds__(256) void merge_out(
        const unsigned short* __restrict__ Opart, const float* __restrict__ Mpart,
        const float* __restrict__ Lpart, const float* __restrict__ x,
        const float* __restrict__ gamma, float* __restrict__ out) {
    __shared__ float tile[64][65];
    int b  = blockIdx.x >> 6;
    int n0 = (blockIdx.x & 63) << 6;
    int tid = threadIdx.x;
    float g = gamma[0];
    int cl  = tid & 63, nl4 = tid >> 6;                // phase 1
    int nl  = tid & 63, cl4 = tid >> 6;                // phase 2
    for (int cc = 0; cc < 4; ++cc) {
        for (int i = 0; i < 16; ++i) {                 // phase 1: coalesced Opart reads
            int n = n0 + i * 4 + nl4;
            int c = (cc << 6) + cl;
            float ms[4], M = -1e30f;
            #pragma unroll
            for (int s = 0; s < 4; ++s) {
                ms[s] = Mpart[(s * 4 + b) * 4096 + n];
                M = fmaxf(M, ms[s]);
            }
            float On = 0.f, L = 0.f;
            #pragma unroll
            for (int s = 0; s < 4; ++s) {
                float e = __expf(ms[s] - M);
                On += e * bf2f(Opart[((size_t)(s * 4 + b) << 20) + n * 256 + c]);
                L  += e * Lpart[(s * 4 + b) * 4096 + n];
            }
            tile[cl][i * 4 + nl4] = g * On / L;
        }
        __syncthreads();
        for (int j = 0; j < 16; ++j) {                 // phase 2: coalesced out writes
            int c = (cc << 6) + j * 4 + cl4;
            int idx = (b << 20) + c * 4096 + n0 + nl;
            out[idx] = tile[j * 4 + cl4][nl] + x[idx];
        }
        __syncthreads();
    }
}

// ---------------------------------------------------------------------------
extern "C" void kernel_launch(void* const* d_in, const int* in_sizes, int n_in,
                              void* d_out, int out_size, void* d_ws, size_t ws_size,
                              hipStream_t stream) {
    const float* x     = (const float*)d_in[0];
    const float* Wq    = (const float*)d_in[1];
    const float* bq    = (const float*)d_in[2];
    const float* Wk    = (const float*)d_in[3];
    const float* bk    = (const float*)d_in[4];
    const float* Wv    = (const float*)d_in[5];
    const float* bv    = (const float*)d_in[6];
    const float* gamma = (const float*)d_in[7];
    float* out = (float*)d_out;

    if (ws_size < 59508736u) return;   // need ~57 MB scratch

    char* ws = (char*)d_ws;
    unsigned short* xbf   = (unsigned short*)(ws);             //  8,388,608 B
    unsigned short* Wt    = (unsigned short*)(ws +  8388608);  //    262,144 B
    float*          bias  = (float*)        (ws +  8650752);   //      2,048 B
    unsigned short* Qrm   = (unsigned short*)(ws +  8652800);  //  4,194,304 B
    unsigned short* Krm   = (unsigned short*)(ws + 12847104);  //  4,194,304 B
    unsigned short* Vbf   = (unsigned short*)(ws + 17041408);  //  8,388,608 B
    unsigned short* Opart = (unsigned short*)(ws + 25430016);  // 33,554,432 B
    float*          Mpart = (float*)        (ws + 58984448);   //    262,144 B
    float*          Lpart = (float*)        (ws + 59246592);   //    262,144 B

    prep_w   <<<512,  256, 0, stream>>>(Wq, bq, Wk, bk, Wv, bv, Wt, bias);
    conv_x   <<<4096, 256, 0, stream>>>(x, xbf);
    proj     <<<256,  256, 0, stream>>>(xbf, Wt, bias, Qrm, Krm, Vbf);
    attn     <<<512,  256, 0, stream>>>(Qrm, Krm, Vbf, Opart, Mpart, Lpart);
    merge_out<<<256,  256, 0, stream>>>(Opart, Mpart, Lpart, x, gamma, out);
}